// Round 2
// baseline (2980.380 us; speedup 1.0000x reference)
//
#include <hip/hip_runtime.h>

// Persistent-kernel DAG-GRU encoder: B=16, S=64, H=1024, C=16.
// G[b,s,o] = hv_s . gate_w[o,:]   computed once per node (state row s is
// written once at step s and never changes). Per step t:
//   phase A: G/M row t-1 (GEMV, fp16 dot2) + h_in masked s-scan
//   phase B: gh = w_hh @ h_in (GEMV) + GRU pointwise -> hv_t
// 2 grid barriers per step, hand-rolled (atomic counter + generation flag).

#define Hh 1024
#define Sx 64
#define Bx 16
#define NB 64
#define NT 512

typedef unsigned int uint;
typedef __attribute__((ext_vector_type(2))) _Float16 half2v;

__device__ __forceinline__ float fdot2(uint w, uint h, float acc) {
#if __has_builtin(__builtin_amdgcn_fdot2)
    return __builtin_amdgcn_fdot2(__builtin_bit_cast(half2v, w),
                                  __builtin_bit_cast(half2v, h), acc, false);
#else
    half2v a = __builtin_bit_cast(half2v, w);
    half2v b = __builtin_bit_cast(half2v, h);
    return acc + (float)a[0] * (float)b[0] + (float)a[1] * (float)b[1];
#endif
}

__device__ __forceinline__ uint packh2(float a, float b) {
    half2v h;
    h[0] = (_Float16)a;
    h[1] = (_Float16)b;
    return __builtin_bit_cast(uint, h);
}

__device__ __forceinline__ float sigm(float x) { return 1.0f / (1.0f + __expf(-x)); }
__device__ __forceinline__ float tanhfast(float x) { return 2.0f / (1.0f + __expf(-2.0f * x)) - 1.0f; }

// device-scope grid barrier; gen must increase by 1 per call, identical across blocks
__device__ __forceinline__ void gridbar(int* cnt, int* rel, int gen) {
    __syncthreads();
    if (threadIdx.x == 0) {
        __threadfence();  // release: drain + wb L2 so other XCDs see our writes
        int old = __hip_atomic_fetch_add(cnt, 1, __ATOMIC_ACQ_REL, __HIP_MEMORY_SCOPE_AGENT);
        if (old == gen * NB - 1) {
            __hip_atomic_store(rel, gen, __ATOMIC_RELEASE, __HIP_MEMORY_SCOPE_AGENT);
        }
        while (__hip_atomic_load(rel, __ATOMIC_ACQUIRE, __HIP_MEMORY_SCOPE_AGENT) < gen) {}
        __threadfence();  // acquire: invalidate L1/L2 so we see others' writes
    }
    __syncthreads();
}

__global__ __launch_bounds__(NT, 1) void enc_kernel(
    const float* __restrict__ dep, const float* __restrict__ ne,
    const float* __restrict__ gate_w, const float* __restrict__ gate_b,
    const float* __restrict__ map_w, const float* __restrict__ map_b,
    const float* __restrict__ w_ih, const float* __restrict__ w_hh,
    const float* __restrict__ b_ih, const float* __restrict__ b_hh,
    const float* __restrict__ l1w, const float* __restrict__ l1b,
    const float* __restrict__ l2w, const float* __restrict__ l2b,
    uint* __restrict__ gwp, uint* __restrict__ mwp,
    uint* __restrict__ whp, uint* __restrict__ lp,
    float* __restrict__ G, float* __restrict__ M,
    unsigned short* __restrict__ hvh, unsigned short* __restrict__ hinh,
    float* __restrict__ hvf, int* __restrict__ bar,
    float* __restrict__ out)
{
    __shared__ float smem[8448];

    const int tid = threadIdx.x;
    const int w = __builtin_amdgcn_readfirstlane(tid >> 6);  // wave id 0..7 (= k-chunk)
    const int lane = tid & 63;
    const int bid = blockIdx.x;
    // XCD-aware task decode: xcd x gets o-tiles {2x,2x+1}, all 4 b-quads
    const int x = bid & 7, bq = (bid >> 3) & 3, oth = bid >> 5;
    const int ot = x * 2 + oth;   // 0..15
    const int o0 = ot * 64;
    const int b0 = bq * 4;

    // opaque zero in a VGPR: forces vector loads for mutable uniform-address data
    int zero;
    asm volatile("v_mov_b32 %0, 0" : "=v"(zero));

    int* cnt = bar;
    int* rel = bar + 1;
    int gen = 0;

    const uint* hvhu = (const uint*)hvh;
    const uint* hinhu = (const uint*)hinh;

    // ---------- preamble: LDS-tiled transpose + fp16 pack of all weights ----------
    // virtual rows: [0,1024) gate_w, [1024,2048) map_w, [2048,5120) w_hh,
    //               [5120,6144) lin11, [6144,7168) lin12.  896 tiles of 64r x 128k.
    for (int tt = bid; tt < 896; tt += NB) {
        int rb = tt >> 3, kt = tt & 7;
        int R0 = rb * 64;
        const float* src;
        uint* dst;
        int col0, Rtot;
        if (R0 < 1024)      { src = gate_w + R0 * 1024;          dst = gwp; col0 = R0;               Rtot = 1024; }
        else if (R0 < 2048) { src = map_w + (R0 - 1024) * 1024;  dst = mwp; col0 = R0 - 1024;        Rtot = 1024; }
        else if (R0 < 5120) { src = w_hh + (R0 - 2048) * 1024;   dst = whp; col0 = R0 - 2048;        Rtot = 3072; }
        else if (R0 < 6144) { src = l1w + (R0 - 5120) * 1024;    dst = lp;  col0 = R0 - 5120;        Rtot = 2048; }
        else                { src = l2w + (R0 - 6144) * 1024;    dst = lp;  col0 = R0 - 6144 + 1024; Rtot = 2048; }
#pragma unroll
        for (int e = 0; e < 16; e++) {
            int idx = tid + e * NT;
            int rl = idx >> 7, kl = idx & 127;
            smem[rl * 130 + kl] = src[rl * 1024 + kt * 128 + kl];
        }
        __syncthreads();
#pragma unroll
        for (int e = 0; e < 8; e++) {
            int idx = tid + e * NT;
            int rl = idx & 63, kpl = idx >> 6;
            float lo = smem[rl * 130 + kpl * 2];
            float hi = smem[rl * 130 + kpl * 2 + 1];
            dst[(kt * 64 + kpl) * Rtot + col0 + rl] = packh2(lo, hi);
        }
        __syncthreads();
    }
    gridbar(cnt, rel, ++gen);

    // ---------- sequential steps ----------
    float h_in_reg = 0.0f;  // valid on tid<256 between phase A and B

    for (int t = 0; t < Sx; t++) {
        // ===== phase A: G/M row t-1 + h_in scan =====
        if (t > 0) {
            float aG[4] = {0, 0, 0, 0}, aM[4] = {0, 0, 0, 0};
            const int kp0 = w * 64;
#pragma unroll 4
            for (int kp = kp0; kp < kp0 + 64; kp++) {
                uint gw = gwp[kp * 1024 + o0 + lane];
                uint mw = mwp[kp * 1024 + o0 + lane];
                uint h0 = hvhu[zero + (b0 + 0) * 512 + kp];
                uint h1 = hvhu[zero + (b0 + 1) * 512 + kp];
                uint h2 = hvhu[zero + (b0 + 2) * 512 + kp];
                uint h3 = hvhu[zero + (b0 + 3) * 512 + kp];
                aG[0] = fdot2(gw, h0, aG[0]); aM[0] = fdot2(mw, h0, aM[0]);
                aG[1] = fdot2(gw, h1, aG[1]); aM[1] = fdot2(mw, h1, aM[1]);
                aG[2] = fdot2(gw, h2, aG[2]); aM[2] = fdot2(mw, h2, aM[2]);
                aG[3] = fdot2(gw, h3, aG[3]); aM[3] = fdot2(mw, h3, aM[3]);
            }
#pragma unroll
            for (int i = 0; i < 4; i++) {
                smem[(w * 4 + i) * 64 + lane] = aG[i];
                smem[2048 + (w * 4 + i) * 64 + lane] = aM[i];
            }
            __syncthreads();
        }

        if (tid < 256) {
            const int ol = tid & 63, bi = tid >> 6;
            const int o = o0 + ol, b = b0 + bi;
            const float gb = gate_b[o], mb = map_b[o];
            const float base = sigm(gb) * mb;
            float acc;
            if (t > 0) {
                float newG = 0, newM = 0;
#pragma unroll
                for (int ww = 0; ww < 8; ww++) {
                    newG += smem[(ww * 4 + bi) * 64 + ol];
                    newM += smem[2048 + (ww * 4 + bi) * 64 + ol];
                }
                G[(b * 64 + (t - 1)) * 1024 + o] = newG;
                M[(b * 64 + (t - 1)) * 1024 + o] = newM;
                acc = 0.0f;
                for (int s4 = 0; s4 < 16; s4++) {
                    float4 mk4 = *(const float4*)&dep[(b * 64 + t) * 64 + s4 * 4];
                    const float* mkp = &mk4.x;
#pragma unroll
                    for (int j = 0; j < 4; j++) {
                        int s = s4 * 4 + j;
                        float mk = mkp[j];
                        if (mk != 0.0f) {  // wave-uniform branch (mask indexed by b,t,s)
                            float Gs = (s == t - 1) ? 0.0f : 0.0f;  // placeholder, real read below
                            Gs = G[(b * 64 + s) * 1024 + o];
                            float Ms = M[(b * 64 + s) * 1024 + o];
                            acc += sigm(Gs + gb) * (Ms + mb);
                        } else {
                            acc += base;
                        }
                    }
                }
            } else {
                acc = 64.0f * base;
            }
            h_in_reg = acc;
            _Float16 hh = (_Float16)acc;
            hinh[b * 1024 + o] = __builtin_bit_cast(unsigned short, hh);
        }
        gridbar(cnt, rel, ++gen);

        // ===== phase B: gh GEMV + GRU pointwise =====
        {
            float ar[4] = {0, 0, 0, 0}, az[4] = {0, 0, 0, 0}, an[4] = {0, 0, 0, 0};
            const int kp0 = w * 64;
#pragma unroll 2
            for (int kp = kp0; kp < kp0 + 64; kp++) {
                uint wr = whp[kp * 3072 + o0 + lane];
                uint wz = whp[kp * 3072 + 1024 + o0 + lane];
                uint wn = whp[kp * 3072 + 2048 + o0 + lane];
                uint h0 = hinhu[zero + (b0 + 0) * 512 + kp];
                uint h1 = hinhu[zero + (b0 + 1) * 512 + kp];
                uint h2 = hinhu[zero + (b0 + 2) * 512 + kp];
                uint h3 = hinhu[zero + (b0 + 3) * 512 + kp];
                ar[0] = fdot2(wr, h0, ar[0]); az[0] = fdot2(wz, h0, az[0]); an[0] = fdot2(wn, h0, an[0]);
                ar[1] = fdot2(wr, h1, ar[1]); az[1] = fdot2(wz, h1, az[1]); an[1] = fdot2(wn, h1, an[1]);
                ar[2] = fdot2(wr, h2, ar[2]); az[2] = fdot2(wz, h2, az[2]); an[2] = fdot2(wn, h2, an[2]);
                ar[3] = fdot2(wr, h3, ar[3]); az[3] = fdot2(wz, h3, az[3]); an[3] = fdot2(wn, h3, an[3]);
            }
#pragma unroll
            for (int i = 0; i < 4; i++) {
                smem[((w * 3 + 0) * 4 + i) * 64 + lane] = ar[i];
                smem[((w * 3 + 1) * 4 + i) * 64 + lane] = az[i];
                smem[((w * 3 + 2) * 4 + i) * 64 + lane] = an[i];
            }
            __syncthreads();
        }
        if (tid < 256) {
            const int ol = tid & 63, bi = tid >> 6;
            const int o = o0 + ol, b = b0 + bi;
            float ghr = 0, ghz = 0, ghn = 0;
#pragma unroll
            for (int ww = 0; ww < 8; ww++) {
                ghr += smem[((ww * 3 + 0) * 4 + bi) * 64 + ol];
                ghz += smem[((ww * 3 + 1) * 4 + bi) * 64 + ol];
                ghn += smem[((ww * 3 + 2) * 4 + bi) * 64 + ol];
            }
            // gi: x @ w_ih.T  (C=16)
            const float* xr = &ne[(b * 64 + t) * 16];
            float4 xa = *(const float4*)&xr[0];
            float4 xb = *(const float4*)&xr[4];
            float4 xc = *(const float4*)&xr[8];
            float4 xd = *(const float4*)&xr[12];
            float gi[3];
#pragma unroll
            for (int g = 0; g < 3; g++) {
                const float* wrow = w_ih + (g * 1024 + o) * 16;
                float4 w0 = *(const float4*)&wrow[0];
                float4 w1 = *(const float4*)&wrow[4];
                float4 w2 = *(const float4*)&wrow[8];
                float4 w3 = *(const float4*)&wrow[12];
                gi[g] = w0.x * xa.x + w0.y * xa.y + w0.z * xa.z + w0.w * xa.w
                      + w1.x * xb.x + w1.y * xb.y + w1.z * xb.z + w1.w * xb.w
                      + w2.x * xc.x + w2.y * xc.y + w2.z * xc.z + w2.w * xc.w
                      + w3.x * xd.x + w3.y * xd.y + w3.z * xd.z + w3.w * xd.w;
            }
            float r = sigm(gi[0] + b_ih[o] + ghr + b_hh[o]);
            float z = sigm(gi[1] + b_ih[1024 + o] + ghz + b_hh[1024 + o]);
            float n = tanhfast(gi[2] + b_ih[2048 + o] + r * (ghn + b_hh[2048 + o]));
            float hv = (1.0f - z) * n + z * h_in_reg;
            hvf[b * 1024 + o] = hv;
            _Float16 hh = (_Float16)hv;
            hvh[b * 1024 + o] = __builtin_bit_cast(unsigned short, hh);
        }
        gridbar(cnt, rel, ++gen);
    }

    // ---------- final: out = [hv | mu | logvar] ----------
    {
        float m1[4] = {0, 0, 0, 0}, m2[4] = {0, 0, 0, 0};
        const int kp0 = w * 64;
#pragma unroll 4
        for (int kp = kp0; kp < kp0 + 64; kp++) {
            uint w1 = lp[kp * 2048 + o0 + lane];
            uint w2 = lp[kp * 2048 + 1024 + o0 + lane];
            uint h0 = hvhu[zero + (b0 + 0) * 512 + kp];
            uint h1 = hvhu[zero + (b0 + 1) * 512 + kp];
            uint h2 = hvhu[zero + (b0 + 2) * 512 + kp];
            uint h3 = hvhu[zero + (b0 + 3) * 512 + kp];
            m1[0] = fdot2(w1, h0, m1[0]); m2[0] = fdot2(w2, h0, m2[0]);
            m1[1] = fdot2(w1, h1, m1[1]); m2[1] = fdot2(w2, h1, m2[1]);
            m1[2] = fdot2(w1, h2, m1[2]); m2[2] = fdot2(w2, h2, m2[2]);
            m1[3] = fdot2(w1, h3, m1[3]); m2[3] = fdot2(w2, h3, m2[3]);
        }
#pragma unroll
        for (int i = 0; i < 4; i++) {
            smem[((w * 2 + 0) * 4 + i) * 64 + lane] = m1[i];
            smem[((w * 2 + 1) * 4 + i) * 64 + lane] = m2[i];
        }
        __syncthreads();
        if (tid < 256) {
            const int ol = tid & 63, bi = tid >> 6;
            const int o = o0 + ol, b = b0 + bi;
            float mu = 0, lv = 0;
#pragma unroll
            for (int ww = 0; ww < 8; ww++) {
                mu += smem[((ww * 2 + 0) * 4 + bi) * 64 + ol];
                lv += smem[((ww * 2 + 1) * 4 + bi) * 64 + ol];
            }
            out[b * 1024 + o] = hvf[b * 1024 + o];
            out[16384 + b * 1024 + o] = mu + l1b[o];
            out[32768 + b * 1024 + o] = lv + l2b[o];
        }
    }
}

extern "C" void kernel_launch(void* const* d_in, const int* in_sizes, int n_in,
                              void* d_out, int out_size, void* d_ws, size_t ws_size,
                              hipStream_t stream) {
    const float* dep     = (const float*)d_in[0];
    const float* ne      = (const float*)d_in[1];
    const float* gate_w  = (const float*)d_in[2];
    const float* gate_b  = (const float*)d_in[3];
    const float* map_w   = (const float*)d_in[4];
    const float* map_b   = (const float*)d_in[5];
    const float* w_ih    = (const float*)d_in[6];
    const float* w_hh    = (const float*)d_in[7];
    const float* b_ih    = (const float*)d_in[8];
    const float* b_hh    = (const float*)d_in[9];
    const float* lin11_w = (const float*)d_in[10];
    const float* lin11_b = (const float*)d_in[11];
    const float* lin12_w = (const float*)d_in[12];
    const float* lin12_b = (const float*)d_in[13];

    float* wsf = (float*)d_ws;
    int* bar = (int*)wsf;                                  // 2 ints (+pad to 16 floats)
    uint* gwp = (uint*)(wsf + 16);                         // 512x1024
    uint* mwp = gwp + 512 * 1024;                          // 512x1024
    uint* whp = mwp + 512 * 1024;                          // 512x3072
    uint* lp  = whp + 512 * 3072;                          // 512x2048
    float* G  = (float*)(lp + 512 * 2048);                 // [16][64][1024]
    float* M  = G + 16 * 64 * 1024;
    float* hvf = M + 16 * 64 * 1024;                       // [16][1024]
    unsigned short* hvh = (unsigned short*)(hvf + 16384);  // [16][1024] fp16
    unsigned short* hinh = hvh + 16384;                    // [16][1024] fp16

    hipMemsetAsync((void*)bar, 0, 8, stream);
    enc_kernel<<<dim3(NB), dim3(NT), 0, stream>>>(
        dep, ne, gate_w, gate_b, map_w, map_b, w_ih, w_hh, b_ih, b_hh,
        lin11_w, lin11_b, lin12_w, lin12_b,
        gwp, mwp, whp, lp, G, M, hvh, hinh, hvf, bar, (float*)d_out);
}

// Round 3
// 1557.334 us; speedup vs baseline: 1.9138x; 1.9138x over previous
//
#include <hip/hip_runtime.h>

// Persistent-kernel DAG-GRU encoder: B=16, S=64, H=1024, C=16.
// Per-node G/M precompute (state row s written once), 64 blocks x 512 thr,
// 2 LEAN grid barriers per step (relaxed agent atomics, no fences).
// Cross-block data (hv, h_in) exchanged via device-coherent (sc0/sc1)
// relaxed atomic loads/stores in transposed [k2][b] layout.

#define NB 64
#define NT 512

typedef unsigned int uint;
typedef __attribute__((ext_vector_type(2))) _Float16 half2v;
typedef __attribute__((ext_vector_type(4))) uint uint4v;

__device__ __forceinline__ float fdot2(uint w, uint h, float acc) {
#if __has_builtin(__builtin_amdgcn_fdot2)
    return __builtin_amdgcn_fdot2(__builtin_bit_cast(half2v, w),
                                  __builtin_bit_cast(half2v, h), acc, false);
#else
    half2v a = __builtin_bit_cast(half2v, w);
    half2v b = __builtin_bit_cast(half2v, h);
    return acc + (float)a[0] * (float)b[0] + (float)a[1] * (float)b[1];
#endif
}

__device__ __forceinline__ uint packh2(float a, float b) {
    half2v h; h[0] = (_Float16)a; h[1] = (_Float16)b;
    return __builtin_bit_cast(uint, h);
}

__device__ __forceinline__ float sigm(float x) { return 1.0f / (1.0f + __expf(-x)); }
__device__ __forceinline__ float tanhfast(float x) { return 2.0f / (1.0f + __expf(-2.0f * x)) - 1.0f; }

// device-coherent (bypasses L1/L2, reads/writes Infinity Cache) accesses
__device__ __forceinline__ uint ld_dev(const uint* p) {
    return __hip_atomic_load(p, __ATOMIC_RELAXED, __HIP_MEMORY_SCOPE_AGENT);
}
__device__ __forceinline__ void st_dev(uint* p, uint v) {
    __hip_atomic_store(p, v, __ATOMIC_RELAXED, __HIP_MEMORY_SCOPE_AGENT);
}

// Lean grid barrier: arrival add + spin on same counter. __syncthreads()
// guarantees each wave drained vmcnt (sc1 stores acked at coherence point)
// before thread 0 signals. flush=true adds a full fence (used ONCE after
// the preamble to write back plain-stored packed weights from L2).
__device__ __forceinline__ void gridbar(int* cnt, int gen, bool flush) {
    __syncthreads();
    if (threadIdx.x == 0) {
        if (flush) __threadfence();
        __hip_atomic_fetch_add(cnt, 1, __ATOMIC_RELAXED, __HIP_MEMORY_SCOPE_AGENT);
        while (__hip_atomic_load(cnt, __ATOMIC_RELAXED, __HIP_MEMORY_SCOPE_AGENT) < gen * NB) {}
    }
    __syncthreads();
}

__global__ __launch_bounds__(NT, 1) void enc_kernel(
    const float* __restrict__ dep, const float* __restrict__ ne,
    const float* __restrict__ gate_w, const float* __restrict__ gate_b,
    const float* __restrict__ map_w, const float* __restrict__ map_b,
    const float* __restrict__ w_ih, const float* __restrict__ w_hh,
    const float* __restrict__ b_ih, const float* __restrict__ b_hh,
    const float* __restrict__ l1w, const float* __restrict__ l1b,
    const float* __restrict__ l2w, const float* __restrict__ l2b,
    uint* __restrict__ gwp, uint* __restrict__ mwp,
    uint* __restrict__ whp, uint* __restrict__ lp,
    float* __restrict__ G, float* __restrict__ M,
    uint* __restrict__ hvT, uint* __restrict__ hinT,
    int* __restrict__ bar, float* __restrict__ out)
{
    // LDS: red[6144]f | packb[256]f | hvS[2048]u | depb[512]u
    // preamble transpose buffer tbuf aliases the first 8448 words.
    __shared__ __align__(16) uint shm[8960];
    float* red   = (float*)shm;          // 6144 floats: GEMV partials + scan partial
    float* packb = (float*)shm + 6144;   // 256 floats: h pack staging
    uint*  hvS   = shm + 6400;           // 2048: staged [kp][4b] operand slice
    uint*  depb  = shm + 8448;           // 512: [bi][t][half] mask bits
    float* tbuf  = (float*)shm;          // preamble transpose scratch (8448 floats)

    const int tid  = threadIdx.x;
    const int w    = __builtin_amdgcn_readfirstlane(tid >> 6);  // wave id = k-chunk
    const int lane = tid & 63;
    const int bid  = blockIdx.x;
    // XCD-aware decode: same-XCD blocks (bid%8) share 2 o-tiles -> L2-hot weights
    const int x = bid & 7, bq = (bid >> 3) & 3, oth = bid >> 5;
    const int o0 = (x * 2 + oth) * 64;  // 64-wide output tile
    const int b0 = bq * 4;              // 4-wide batch quad

    int* cnt = bar;
    int gen = 0;

    float* Gb = G + bid * 16384;  // block-local [bi][s][ol] fp32
    float* Mb = M + bid * 16384;

    // ---------- preamble 1: mask bits ----------
    {
        const int bi = tid >> 7, tt = (tid >> 1) & 63, half = tid & 1;
        const float* dp = dep + (((b0 + bi) * 64 + tt) * 64) + half * 32;
        uint bits = 0;
        for (int s = 0; s < 32; s++) bits |= (dp[s] != 0.0f) ? (1u << s) : 0u;
        depb[tid] = bits;  // tid == bi*128 + tt*2 + half
    }

    // ---------- preamble 2: weight transpose + fp16 pack ----------
    // virtual rows: [0,1024) gate_w, [1024,2048) map_w, [2048,5120) w_hh,
    // [5120,6144) lin11, [6144,7168) lin12.  896 tiles of 64r x 128k.
    for (int tt = bid; tt < 896; tt += NB) {
        int rb = tt >> 3, kt = tt & 7;
        int R0 = rb * 64;
        const float* src; uint* dst; int col0, Rtot;
        if (R0 < 1024)      { src = gate_w + R0 * 1024;         dst = gwp; col0 = R0;               Rtot = 1024; }
        else if (R0 < 2048) { src = map_w + (R0 - 1024) * 1024; dst = mwp; col0 = R0 - 1024;        Rtot = 1024; }
        else if (R0 < 5120) { src = w_hh + (R0 - 2048) * 1024;  dst = whp; col0 = R0 - 2048;        Rtot = 3072; }
        else if (R0 < 6144) { src = l1w + (R0 - 5120) * 1024;   dst = lp;  col0 = R0 - 5120;        Rtot = 2048; }
        else                { src = l2w + (R0 - 6144) * 1024;   dst = lp;  col0 = R0 - 6144 + 1024; Rtot = 2048; }
#pragma unroll
        for (int e = 0; e < 16; e++) {
            int idx = tid + e * NT;
            int rl = idx >> 7, kl = idx & 127;
            tbuf[rl * 130 + kl] = src[rl * 1024 + kt * 128 + kl];
        }
        __syncthreads();
#pragma unroll
        for (int e = 0; e < 8; e++) {
            int idx = tid + e * NT;
            int rl = idx & 63, kpl = idx >> 6;
            dst[(kt * 64 + kpl) * Rtot + col0 + rl] =
                packh2(tbuf[rl * 130 + kpl * 2], tbuf[rl * 130 + kpl * 2 + 1]);
        }
        __syncthreads();
    }
    gridbar(cnt, ++gen, true);  // ONE fenced barrier: flush packed weights

    // hoisted per-thread constants (thread role: ol/bi for consumer+scan)
    const int ol = tid & 63, bi = (tid >> 6) & 3, xy = tid >> 8;
    const int o = o0 + ol, b = b0 + bi;
    const float gb = gate_b[o], mb = map_b[o];
    const float base = sigm(gb) * mb;
    const float bir = b_ih[o], biz = b_ih[1024 + o], bin_ = b_ih[2048 + o];
    const float bhr = b_hh[o], bhz = b_hh[1024 + o], bhn = b_hh[2048 + o];

    float h_in_reg = 0.0f;  // valid on tid<256 between phase A and B

    for (int t = 0; t < 64; t++) {
        // ===== phase A: G/M row t-1 GEMV + masked h_in scan =====
        if (t > 0) {
            {   // stage hvT slice [kp=tid][b0..b0+3] -> LDS
                const uint* src = hvT + tid * 16 + b0;
                uint4v h;
                h[0] = ld_dev(src + 0); h[1] = ld_dev(src + 1);
                h[2] = ld_dev(src + 2); h[3] = ld_dev(src + 3);
                *(uint4v*)&hvS[tid * 4] = h;
            }
            __syncthreads();
            float aG[4] = {0, 0, 0, 0}, aM[4] = {0, 0, 0, 0};
            const int kp0 = w * 64;
#pragma unroll 4
            for (int kp = kp0; kp < kp0 + 64; kp++) {
                uint gw = gwp[kp * 1024 + o0 + lane];
                uint mw = mwp[kp * 1024 + o0 + lane];
                uint4v h4 = *(const uint4v*)&hvS[kp * 4];  // broadcast ds_read_b128
                aG[0] = fdot2(gw, h4[0], aG[0]); aM[0] = fdot2(mw, h4[0], aM[0]);
                aG[1] = fdot2(gw, h4[1], aG[1]); aM[1] = fdot2(mw, h4[1], aM[1]);
                aG[2] = fdot2(gw, h4[2], aG[2]); aM[2] = fdot2(mw, h4[2], aM[2]);
                aG[3] = fdot2(gw, h4[3], aG[3]); aM[3] = fdot2(mw, h4[3], aM[3]);
            }
#pragma unroll
            for (int i = 0; i < 4; i++) {
                red[(w * 4 + i) * 64 + lane] = aG[i];
                red[2048 + (w * 4 + i) * 64 + lane] = aM[i];
            }
            __syncthreads();
        }

        if (t > 0 && tid < 256) {  // reduce + write G/M row t-1
            float newG = 0, newM = 0;
#pragma unroll
            for (int ww = 0; ww < 8; ww++) {
                newG += red[(ww * 4 + bi) * 64 + ol];
                newM += red[2048 + (ww * 4 + bi) * 64 + ol];
            }
            Gb[(bi * 64 + (t - 1)) * 64 + ol] = newG;
            Mb[(bi * 64 + (t - 1)) * 64 + ol] = newM;
        }
        __syncthreads();  // G/M row visible to all waves (same CU)

        {   // masked scan, all 512 threads: X half s in [0,32), Y half [32,64)
            uint bits = depb[bi * 128 + t * 2 + xy];
            const float* Gp = Gb + bi * 4096 + xy * 2048 + ol;
            const float* Mp = Mb + bi * 4096 + xy * 2048 + ol;
            float partial = 0.0f;
#pragma unroll 8
            for (int j = 0; j < 32; j++) {
                float Gs = Gp[j * 64], Ms = Mp[j * 64];
                float term = ((bits >> j) & 1u) ? (sigm(Gs + gb) * (Ms + mb)) : base;
                partial += term;
            }
            if (tid >= 256) red[4096 + bi * 64 + ol] = partial;
            __syncthreads();
            if (tid < 256) {
                float h_in = partial + red[4096 + bi * 64 + ol];
                h_in_reg = h_in;
                packb[bi * 64 + ol] = h_in;
            }
        }
        __syncthreads();
        if (tid < 128) {  // pack h_in -> hinT[k2][b], device-coherent
            int j = tid & 31, bi2 = tid >> 5;
            uint pk = packh2(packb[bi2 * 64 + 2 * j], packb[bi2 * 64 + 2 * j + 1]);
            st_dev(hinT + (o0 / 2 + j) * 16 + b0 + bi2, pk);
        }
        gridbar(cnt, ++gen, false);

        // ===== phase B: gh GEMV + GRU pointwise =====
        {   // stage hinT slice -> LDS
            const uint* src = hinT + tid * 16 + b0;
            uint4v h;
            h[0] = ld_dev(src + 0); h[1] = ld_dev(src + 1);
            h[2] = ld_dev(src + 2); h[3] = ld_dev(src + 3);
            *(uint4v*)&hvS[tid * 4] = h;
        }
        __syncthreads();
        {
            float ar[4] = {0, 0, 0, 0}, az[4] = {0, 0, 0, 0}, an[4] = {0, 0, 0, 0};
            const int kp0 = w * 64;
#pragma unroll 2
            for (int kp = kp0; kp < kp0 + 64; kp++) {
                uint wr = whp[kp * 3072 + o0 + lane];
                uint wz = whp[kp * 3072 + 1024 + o0 + lane];
                uint wn = whp[kp * 3072 + 2048 + o0 + lane];
                uint4v h4 = *(const uint4v*)&hvS[kp * 4];
                ar[0] = fdot2(wr, h4[0], ar[0]); az[0] = fdot2(wz, h4[0], az[0]); an[0] = fdot2(wn, h4[0], an[0]);
                ar[1] = fdot2(wr, h4[1], ar[1]); az[1] = fdot2(wz, h4[1], az[1]); an[1] = fdot2(wn, h4[1], an[1]);
                ar[2] = fdot2(wr, h4[2], ar[2]); az[2] = fdot2(wz, h4[2], az[2]); an[2] = fdot2(wn, h4[2], an[2]);
                ar[3] = fdot2(wr, h4[3], ar[3]); az[3] = fdot2(wz, h4[3], az[3]); an[3] = fdot2(wn, h4[3], an[3]);
            }
#pragma unroll
            for (int i = 0; i < 4; i++) {
                red[((w * 3 + 0) * 4 + i) * 64 + lane] = ar[i];
                red[((w * 3 + 1) * 4 + i) * 64 + lane] = az[i];
                red[((w * 3 + 2) * 4 + i) * 64 + lane] = an[i];
            }
            __syncthreads();
        }
        if (tid < 256) {
            float ghr = 0, ghz = 0, ghn = 0;
#pragma unroll
            for (int ww = 0; ww < 8; ww++) {
                ghr += red[((ww * 3 + 0) * 4 + bi) * 64 + ol];
                ghz += red[((ww * 3 + 1) * 4 + bi) * 64 + ol];
                ghn += red[((ww * 3 + 2) * 4 + bi) * 64 + ol];
            }
            // gi = x @ w_ih.T (C=16), w_ih slice is L1-resident
            const float* xr = &ne[(b * 64 + t) * 16];
            float4 xa = *(const float4*)&xr[0];
            float4 xb = *(const float4*)&xr[4];
            float4 xc = *(const float4*)&xr[8];
            float4 xd = *(const float4*)&xr[12];
            float gi[3];
#pragma unroll
            for (int g = 0; g < 3; g++) {
                const float* wrow = w_ih + (g * 1024 + o) * 16;
                float4 w0 = *(const float4*)&wrow[0];
                float4 w1 = *(const float4*)&wrow[4];
                float4 w2 = *(const float4*)&wrow[8];
                float4 w3 = *(const float4*)&wrow[12];
                gi[g] = w0.x * xa.x + w0.y * xa.y + w0.z * xa.z + w0.w * xa.w
                      + w1.x * xb.x + w1.y * xb.y + w1.z * xb.z + w1.w * xb.w
                      + w2.x * xc.x + w2.y * xc.y + w2.z * xc.z + w2.w * xc.w
                      + w3.x * xd.x + w3.y * xd.y + w3.z * xd.z + w3.w * xd.w;
            }
            float r = sigm(gi[0] + bir + ghr + bhr);
            float z = sigm(gi[1] + biz + ghz + bhz);
            float n = tanhfast(gi[2] + bin_ + r * (ghn + bhn));
            float hv = (1.0f - z) * n + z * h_in_reg;
            if (t == 63) out[b * 1024 + o] = hv;
            packb[bi * 64 + ol] = hv;
        }
        __syncthreads();
        if (tid < 128) {  // pack hv -> hvT[k2][b]
            int j = tid & 31, bi2 = tid >> 5;
            uint pk = packh2(packb[bi2 * 64 + 2 * j], packb[bi2 * 64 + 2 * j + 1]);
            st_dev(hvT + (o0 / 2 + j) * 16 + b0 + bi2, pk);
        }
        gridbar(cnt, ++gen, false);
    }

    // ---------- final: mu / logvar ----------
    {
        {   // stage final hvT slice
            const uint* src = hvT + tid * 16 + b0;
            uint4v h;
            h[0] = ld_dev(src + 0); h[1] = ld_dev(src + 1);
            h[2] = ld_dev(src + 2); h[3] = ld_dev(src + 3);
            *(uint4v*)&hvS[tid * 4] = h;
        }
        __syncthreads();
        float m1[4] = {0, 0, 0, 0}, m2[4] = {0, 0, 0, 0};
        const int kp0 = w * 64;
#pragma unroll 4
        for (int kp = kp0; kp < kp0 + 64; kp++) {
            uint w1 = lp[kp * 2048 + o0 + lane];
            uint w2 = lp[kp * 2048 + 1024 + o0 + lane];
            uint4v h4 = *(const uint4v*)&hvS[kp * 4];
            m1[0] = fdot2(w1, h4[0], m1[0]); m2[0] = fdot2(w2, h4[0], m2[0]);
            m1[1] = fdot2(w1, h4[1], m1[1]); m2[1] = fdot2(w2, h4[1], m2[1]);
            m1[2] = fdot2(w1, h4[2], m1[2]); m2[2] = fdot2(w2, h4[2], m2[2]);
            m1[3] = fdot2(w1, h4[3], m1[3]); m2[3] = fdot2(w2, h4[3], m2[3]);
        }
#pragma unroll
        for (int i = 0; i < 4; i++) {
            red[((w * 2 + 0) * 4 + i) * 64 + lane] = m1[i];
            red[((w * 2 + 1) * 4 + i) * 64 + lane] = m2[i];
        }
        __syncthreads();
        if (tid < 256) {
            float mu = 0, lv = 0;
#pragma unroll
            for (int ww = 0; ww < 8; ww++) {
                mu += red[((ww * 2 + 0) * 4 + bi) * 64 + ol];
                lv += red[((ww * 2 + 1) * 4 + bi) * 64 + ol];
            }
            out[16384 + b * 1024 + o] = mu + l1b[o];
            out[32768 + b * 1024 + o] = lv + l2b[o];
        }
    }
}

extern "C" void kernel_launch(void* const* d_in, const int* in_sizes, int n_in,
                              void* d_out, int out_size, void* d_ws, size_t ws_size,
                              hipStream_t stream) {
    const float* dep     = (const float*)d_in[0];
    const float* ne      = (const float*)d_in[1];
    const float* gate_w  = (const float*)d_in[2];
    const float* gate_b  = (const float*)d_in[3];
    const float* map_w   = (const float*)d_in[4];
    const float* map_b   = (const float*)d_in[5];
    const float* w_ih    = (const float*)d_in[6];
    const float* w_hh    = (const float*)d_in[7];
    const float* b_ih    = (const float*)d_in[8];
    const float* b_hh    = (const float*)d_in[9];
    const float* lin11_w = (const float*)d_in[10];
    const float* lin11_b = (const float*)d_in[11];
    const float* lin12_w = (const float*)d_in[12];
    const float* lin12_b = (const float*)d_in[13];

    float* wsf = (float*)d_ws;
    int* bar  = (int*)wsf;                       // 16 B
    uint* gwp = (uint*)(wsf + 16);               // 512x1024
    uint* mwp = gwp + 512 * 1024;                // 512x1024
    uint* whp = mwp + 512 * 1024;                // 512x3072
    uint* lp  = whp + 512 * 3072;                // 512x2048
    float* G  = (float*)(lp + 512 * 2048);       // 64 blocks x [4][64][64]
    float* M  = G + NB * 16384;
    uint* hvT  = (uint*)(M + NB * 16384);        // [512][16]
    uint* hinT = hvT + 8192;                     // [512][16]

    hipMemsetAsync((void*)bar, 0, 16, stream);
    enc_kernel<<<dim3(NB), dim3(NT), 0, stream>>>(
        dep, ne, gate_w, gate_b, map_w, map_b, w_ih, w_hh, b_ih, b_hh,
        lin11_w, lin11_b, lin12_w, lin12_b,
        gwp, mwp, whp, lp, G, M, hvT, hinT, bar, (float*)d_out);
}

// Round 7
// 1064.775 us; speedup vs baseline: 2.7991x; 1.4626x over previous
//
#include <hip/hip_runtime.h>

// DAG-GRU encoder, dispatch-independent persistent kernel + separate mu/logvar
// GEMV kernel. B=16, S=64, H=1024, C=16.
// enc_kernel: 8 groups (= blockIdx>>5) x 32 blocks; group g owns batches
// {2g,2g+1}. Each block: 32-o output tile, all 5 weight rows in VGPRs as fp16
// pairs. Per step: phase A (G/M row GEMV + LDS masked scan -> h_in), phase B
// (gh GEMV + GRU pointwise -> hv). Cross-block exchange via sc0/sc1 ops with
// release/acquire fences around single-writer flags. hv written to out in f32.
// kF: separate kernel, reads the VALIDATED f32 hv from out and computes
// mu/logvar (kernel boundary = full coherence; sidesteps the r5/r6 epilogue bug).

#define NT 512
#define NBLK 256

typedef unsigned int uint;
typedef __attribute__((ext_vector_type(2))) _Float16 half2v;
typedef __attribute__((ext_vector_type(4))) uint uint4v;

__device__ __forceinline__ float fdot2(uint w, uint h, float acc) {
#if __has_builtin(__builtin_amdgcn_fdot2)
    return __builtin_amdgcn_fdot2(__builtin_bit_cast(half2v, w),
                                  __builtin_bit_cast(half2v, h), acc, false);
#else
    half2v a = __builtin_bit_cast(half2v, w);
    half2v b = __builtin_bit_cast(half2v, h);
    return acc + (float)a[0] * (float)b[0] + (float)a[1] * (float)b[1];
#endif
}

__device__ __forceinline__ uint packh2(float a, float b) {
    half2v h; h[0] = (_Float16)a; h[1] = (_Float16)b;
    return __builtin_bit_cast(uint, h);
}

__device__ __forceinline__ float sigm(float x) { return 1.0f / (1.0f + __expf(-x)); }
__device__ __forceinline__ float tanhfast(float x) { return 2.0f / (1.0f + __expf(-2.0f * x)) - 1.0f; }

// 8x dwordx4 device-coherent loads (bypass L1+L2 -> Infinity Cache) + wait
#define LD8_DEV(hx, baseptr)                                                   \
    asm volatile("global_load_dwordx4 %0, %8, off sc0 sc1\n\t"                 \
                 "global_load_dwordx4 %1, %8, off offset:16 sc0 sc1\n\t"       \
                 "global_load_dwordx4 %2, %8, off offset:32 sc0 sc1\n\t"       \
                 "global_load_dwordx4 %3, %8, off offset:48 sc0 sc1\n\t"       \
                 "global_load_dwordx4 %4, %8, off offset:64 sc0 sc1\n\t"       \
                 "global_load_dwordx4 %5, %8, off offset:80 sc0 sc1\n\t"       \
                 "global_load_dwordx4 %6, %8, off offset:96 sc0 sc1\n\t"       \
                 "global_load_dwordx4 %7, %8, off offset:112 sc0 sc1\n\t"      \
                 "s_waitcnt vmcnt(0)"                                          \
                 : "=&v"(hx[0]), "=&v"(hx[1]), "=&v"(hx[2]), "=&v"(hx[3]),     \
                   "=&v"(hx[4]), "=&v"(hx[5]), "=&v"(hx[6]), "=&v"(hx[7])      \
                 : "v"(baseptr) : "memory")

__device__ __forceinline__ void st_dev_wait(uint* p, uint v) {
    asm volatile("global_store_dword %0, %1, off sc0 sc1\n\ts_waitcnt vmcnt(0)"
                 :: "v"(p), "v"(v) : "memory");
}

__device__ __forceinline__ void st_flag_rel(int* p, int v) {
    __builtin_amdgcn_fence(__ATOMIC_RELEASE, "agent");
    asm volatile("global_store_dword %0, %1, off sc0 sc1\n\ts_waitcnt vmcnt(0)"
                 :: "v"(p), "v"(v) : "memory");
}

__device__ __forceinline__ void wait_flags(const int* fl, int gen) {
    if (threadIdx.x < 64) {
        const int lane = threadIdx.x;
        bool done;
        do {
            int v = gen;
            if (lane < 32) {
                const int* pp = fl + lane;
                asm volatile("global_load_dword %0, %1, off sc0 sc1\n\ts_waitcnt vmcnt(0)"
                             : "=v"(v) : "v"(pp) : "memory");
            }
            done = __all(v >= gen);
        } while (!done);
        __builtin_amdgcn_fence(__ATOMIC_ACQUIRE, "agent");
    }
    __syncthreads();
}

__device__ __forceinline__ void loadw(uint* arr, const float* rowk) {
    const float4* s4 = (const float4*)rowk;
#pragma unroll
    for (int j = 0; j < 16; j++) {
        float4 v = s4[j];
        arr[2 * j]     = packh2(v.x, v.y);
        arr[2 * j + 1] = packh2(v.z, v.w);
    }
}

__global__ __launch_bounds__(NT) void enc_kernel(
    const float* __restrict__ dep, const float* __restrict__ ne,
    const float* __restrict__ gate_w, const float* __restrict__ gate_b,
    const float* __restrict__ map_w, const float* __restrict__ map_b,
    const float* __restrict__ w_ih, const float* __restrict__ w_hh,
    const float* __restrict__ b_ih, const float* __restrict__ b_hh,
    int* __restrict__ flags, uint* __restrict__ hv_ex, uint* __restrict__ hin_ex,
    float* __restrict__ out)
{
    __shared__ __align__(16) float smem[13888];
    float* GM   = smem;                   // [4][64][33]: (mat*2+b, s, ol) f32
    float* red  = smem + 8448;            // 1536: cross-wave partials
    float* hbuf = smem + 9984;            // [2][32]: h_in / hv staging
    float* wihb = smem + 10048;           // [3][32][16] w_ih slice
    float* neb  = smem + 11584;           // [2][64][16] node_encoding slice
    uint*  depb = (uint*)(smem + 13632);  // [2][64][2] mask bits

    const int tid = threadIdx.x;
    const int bid = blockIdx.x;
    const int gid = bid >> 5;          // group = batch pair (dispatch-independent)
    const int p   = bid & 31;          // o-tile slot in group
    const int o0  = p * 32;
    const int bg0 = gid * 2;

    int*  fl   = flags  + gid * 32;
    uint* hvx  = hv_ex  + gid * 1024;  // [2][512] uints (fp16 pairs)
    uint* hinx = hin_ex + gid * 1024;

    const int w     = tid >> 6;        // wave = k-chunk of 128
    const int lane  = tid & 63;
    const int ol2   = lane >> 1;       // GEMV lane's o within tile
    const int kh    = lane & 1;
    const int og    = o0 + ol2;
    const int kbase = w * 128 + kh * 64;

    // ---- weights -> registers (fp16 packed), 160 VGPRs ----
    uint wG[32], wM[32], wR[32], wZ[32], wN[32];
    loadw(wG, gate_w + og * 1024 + kbase);
    loadw(wM, map_w + og * 1024 + kbase);
    loadw(wR, w_hh + og * 1024 + kbase);
    loadw(wZ, w_hh + (1024 + og) * 1024 + kbase);
    loadw(wN, w_hh + (2048 + og) * 1024 + kbase);

    // ---- LDS tables ----
    if (tid < 256) {  // dep bitmask: [b][t][half32]
        int b = tid >> 7, tt = (tid >> 1) & 63, hf = tid & 1;
        const float* dp = dep + (((bg0 + b) * 64 + tt) * 64) + hf * 32;
        uint bits = 0;
        for (int s = 0; s < 32; s++) bits |= (dp[s] != 0.0f) ? (1u << s) : 0u;
        depb[tid] = bits;
    }
#pragma unroll
    for (int e = 0; e < 3; e++) {     // w_ih slice [g][ol][c]
        int idx = tid + e * 512;
        int g = idx >> 9, r = idx & 511;
        wihb[idx] = w_ih[(g * 1024 + o0 + (r >> 4)) * 16 + (r & 15)];
    }
#pragma unroll
    for (int e = 0; e < 4; e++) {     // ne slice [b][t][c]
        int idx = tid + e * 512;
        int b = idx >> 10, r = idx & 1023;
        neb[idx] = ne[(bg0 + b) * 1024 + r];
    }

    // ---- hoisted per-thread scalars ----
    const int ol_s = (tid >> 3) & 31;
    const int b_s  = tid >> 8;
    const int soct = tid & 7;
    const float gb_s   = gate_b[o0 + ol_s];
    const float mb_s   = map_b[o0 + ol_s];
    const float base_s = sigm(gb_s) * mb_s;
    const int ol_c = tid & 31, b_c = (tid >> 5) & 1;
    const int oc = o0 + ol_c;
    const float bir = b_ih[oc], biz = b_ih[1024 + oc], bin_ = b_ih[2048 + oc];
    const float bhr = b_hh[oc], bhz = b_hh[1024 + oc], bhn = b_hh[2048 + oc];
    __syncthreads();

    for (int t = 0; t < 64; t++) {
        // ===== phase A: G/M row t-1 GEMV (regs) + masked scan -> h_in =====
        if (t > 0) {
            wait_flags(fl, 2 * t);     // hv of step t-1 published everywhere
            float aG0 = 0, aG1 = 0, aM0 = 0, aM1 = 0;
            {
                uint4v hx[8];
                LD8_DEV(hx, hvx + w * 64 + kh * 32);           // b0 hv slice
#pragma unroll
                for (int j = 0; j < 8; j++)
#pragma unroll
                    for (int q = 0; q < 4; q++) {
                        uint h = hx[j][q];
                        aG0 = fdot2(wG[j * 4 + q], h, aG0);
                        aM0 = fdot2(wM[j * 4 + q], h, aM0);
                    }
                LD8_DEV(hx, hvx + 512 + w * 64 + kh * 32);     // b1
#pragma unroll
                for (int j = 0; j < 8; j++)
#pragma unroll
                    for (int q = 0; q < 4; q++) {
                        uint h = hx[j][q];
                        aG1 = fdot2(wG[j * 4 + q], h, aG1);
                        aM1 = fdot2(wM[j * 4 + q], h, aM1);
                    }
            }
            aG0 += __shfl_xor(aG0, 1, 64); aG1 += __shfl_xor(aG1, 1, 64);
            aM0 += __shfl_xor(aM0, 1, 64); aM1 += __shfl_xor(aM1, 1, 64);
            if (kh == 0) {
                red[(w * 4 + 0) * 32 + ol2] = aG0;
                red[(w * 4 + 1) * 32 + ol2] = aG1;
                red[(w * 4 + 2) * 32 + ol2] = aM0;
                red[(w * 4 + 3) * 32 + ol2] = aM1;
            }
            __syncthreads();
            if (tid < 128) {   // mb2 = tid>>5: {G b0, G b1, M b0, M b1}
                int mb2 = tid >> 5, olr = tid & 31;
                float s = 0;
#pragma unroll
                for (int ww = 0; ww < 8; ww++) s += red[(ww * 4 + mb2) * 32 + olr];
                GM[(mb2 * 64 + (t - 1)) * 33 + olr] = s;
            }
            __syncthreads();
        }

        {   // masked scan: 8 threads per (b,o), 8 s each; GM in LDS
            uint bl = depb[b_s * 128 + t * 2 + (soct >> 2)];
            uint bits8 = (bl >> ((soct & 3) * 8)) & 0xFFu;
            const float* Gp = GM + (b_s * 64 + soct * 8) * 33 + ol_s;
            const float* Mp = GM + ((2 + b_s) * 64 + soct * 8) * 33 + ol_s;
            float part = 0.0f;
#pragma unroll
            for (int j = 0; j < 8; j++) {
                float Gv = Gp[j * 33], Mv = Mp[j * 33];
                float term = ((bits8 >> j) & 1u) ? (sigm(Gv + gb_s) * (Mv + mb_s)) : base_s;
                part += term;
            }
            part += __shfl_xor(part, 1, 64);
            part += __shfl_xor(part, 2, 64);
            part += __shfl_xor(part, 4, 64);
            if ((tid & 7) == 0) hbuf[b_s * 32 + ol_s] = part;
        }
        __syncthreads();
        if (tid < 32) {   // publish h_in slice (fp16 pairs)
            int bb = tid >> 4, j = tid & 15;
            uint pk = packh2(hbuf[bb * 32 + 2 * j], hbuf[bb * 32 + 2 * j + 1]);
            st_dev_wait(hinx + bb * 512 + p * 16 + j, pk);
        }
        __syncthreads();
        if (tid == 0) st_flag_rel(fl + p, 2 * t + 1);

        // ===== phase B: gh GEMV (regs) + GRU pointwise -> hv =====
        wait_flags(fl, 2 * t + 1);
        float ar0 = 0, ar1 = 0, az0 = 0, az1 = 0, an0 = 0, an1 = 0;
        {
            uint4v hx[8];
            LD8_DEV(hx, hinx + w * 64 + kh * 32);
#pragma unroll
            for (int j = 0; j < 8; j++)
#pragma unroll
                for (int q = 0; q < 4; q++) {
                    uint h = hx[j][q];
                    ar0 = fdot2(wR[j * 4 + q], h, ar0);
                    az0 = fdot2(wZ[j * 4 + q], h, az0);
                    an0 = fdot2(wN[j * 4 + q], h, an0);
                }
            LD8_DEV(hx, hinx + 512 + w * 64 + kh * 32);
#pragma unroll
            for (int j = 0; j < 8; j++)
#pragma unroll
                for (int q = 0; q < 4; q++) {
                    uint h = hx[j][q];
                    ar1 = fdot2(wR[j * 4 + q], h, ar1);
                    az1 = fdot2(wZ[j * 4 + q], h, az1);
                    an1 = fdot2(wN[j * 4 + q], h, an1);
                }
        }
        ar0 += __shfl_xor(ar0, 1, 64); ar1 += __shfl_xor(ar1, 1, 64);
        az0 += __shfl_xor(az0, 1, 64); az1 += __shfl_xor(az1, 1, 64);
        an0 += __shfl_xor(an0, 1, 64); an1 += __shfl_xor(an1, 1, 64);
        if (kh == 0) {
            red[(w * 6 + 0) * 32 + ol2] = ar0;
            red[(w * 6 + 1) * 32 + ol2] = ar1;
            red[(w * 6 + 2) * 32 + ol2] = az0;
            red[(w * 6 + 3) * 32 + ol2] = az1;
            red[(w * 6 + 4) * 32 + ol2] = an0;
            red[(w * 6 + 5) * 32 + ol2] = an1;
        }
        __syncthreads();
        if (tid < 64) {
            float ghr = 0, ghz = 0, ghn = 0;
#pragma unroll
            for (int ww = 0; ww < 8; ww++) {
                ghr += red[(ww * 6 + 0 + b_c) * 32 + ol_c];
                ghz += red[(ww * 6 + 2 + b_c) * 32 + ol_c];
                ghn += red[(ww * 6 + 4 + b_c) * 32 + ol_c];
            }
            float gi0 = 0, gi1 = 0, gi2 = 0;
#pragma unroll
            for (int c = 0; c < 16; c++) {
                float xv = neb[b_c * 1024 + t * 16 + c];
                gi0 += wihb[ol_c * 16 + c] * xv;
                gi1 += wihb[512 + ol_c * 16 + c] * xv;
                gi2 += wihb[1024 + ol_c * 16 + c] * xv;
            }
            float h_in = hbuf[b_c * 32 + ol_c];
            float r = sigm(gi0 + bir + ghr + bhr);
            float z = sigm(gi1 + biz + ghz + bhz);
            float n = tanhfast(gi2 + bin_ + r * (ghn + bhn));
            float hv = (1.0f - z) * n + z * h_in;
            if (t == 63) out[(bg0 + b_c) * 1024 + oc] = hv;
            hbuf[b_c * 32 + ol_c] = hv;
        }
        __syncthreads();
        if (t < 63) {
            if (tid < 32) {   // publish hv slice
                int bb = tid >> 4, j = tid & 15;
                uint pk = packh2(hbuf[bb * 32 + 2 * j], hbuf[bb * 32 + 2 * j + 1]);
                st_dev_wait(hvx + bb * 512 + p * 16 + j, pk);
            }
            __syncthreads();
            if (tid == 0) st_flag_rel(fl + p, 2 * t + 2);
        }
    }
    // mu/logvar computed by kF (separate dispatch) from the f32 hv in out.
}

__device__ __forceinline__ float wave_sum(float v) {
    v += __shfl_xor(v, 32, 64);
    v += __shfl_xor(v, 16, 64);
    v += __shfl_xor(v, 8, 64);
    v += __shfl_xor(v, 4, 64);
    v += __shfl_xor(v, 2, 64);
    v += __shfl_xor(v, 1, 64);
    return v;
}

// mu/logvar: out[16K..32K) = hv @ l1w^T + b1, out[32K..48K) = hv @ l2w^T + b2.
// Reads the f32 hv at out[0..16K) written by enc_kernel (round-1-proven code).
__global__ __launch_bounds__(256) void kF(
    float* out, const float* __restrict__ w1, const float* __restrict__ b1,
    const float* __restrict__ w2, const float* __restrict__ b2)
{
    const int wid = threadIdx.x >> 6;
    const int kl = threadIdx.x & 63;
    const int o = blockIdx.x * 2 + (wid >> 1);
    const int b0 = (wid & 1) * 8;

    float w1v[16], w2v[16];
#pragma unroll
    for (int i = 0; i < 16; i++) {
        w1v[i] = w1[o * 1024 + kl + 64 * i];
        w2v[i] = w2[o * 1024 + kl + 64 * i];
    }
    for (int b = b0; b < b0 + 8; b++) {
        float p1 = 0.0f, p2 = 0.0f;
#pragma unroll
        for (int i = 0; i < 16; i++) {
            float h = out[b * 1024 + kl + 64 * i];
            p1 += h * w1v[i];
            p2 += h * w2v[i];
        }
        p1 = wave_sum(p1);
        p2 = wave_sum(p2);
        if (kl == 0) {
            out[16384 + b * 1024 + o] = p1 + b1[o];
            out[32768 + b * 1024 + o] = p2 + b2[o];
        }
    }
}

extern "C" void kernel_launch(void* const* d_in, const int* in_sizes, int n_in,
                              void* d_out, int out_size, void* d_ws, size_t ws_size,
                              hipStream_t stream) {
    const float* dep     = (const float*)d_in[0];
    const float* ne      = (const float*)d_in[1];
    const float* gate_w  = (const float*)d_in[2];
    const float* gate_b  = (const float*)d_in[3];
    const float* map_w   = (const float*)d_in[4];
    const float* map_b   = (const float*)d_in[5];
    const float* w_ih    = (const float*)d_in[6];
    const float* w_hh    = (const float*)d_in[7];
    const float* b_ih    = (const float*)d_in[8];
    const float* b_hh    = (const float*)d_in[9];
    const float* lin11_w = (const float*)d_in[10];
    const float* lin11_b = (const float*)d_in[11];
    const float* lin12_w = (const float*)d_in[12];
    const float* lin12_b = (const float*)d_in[13];

    int* wsI = (int*)d_ws;
    int* flags   = wsI;                      // [8][32] ints
    uint* hv_ex  = (uint*)(wsI + 256);       // [8][2][512]
    uint* hin_ex = hv_ex + 8192;             // [8][2][512]
    float* outp  = (float*)d_out;

    hipMemsetAsync((void*)flags, 0, 256 * 4, stream);

    void* args[] = {
        (void*)&dep, (void*)&ne, (void*)&gate_w, (void*)&gate_b,
        (void*)&map_w, (void*)&map_b, (void*)&w_ih, (void*)&w_hh,
        (void*)&b_ih, (void*)&b_hh,
        (void*)&flags, (void*)&hv_ex, (void*)&hin_ex, (void*)&outp,
    };
    hipError_t e = hipLaunchCooperativeKernel((void*)enc_kernel, dim3(NBLK), dim3(NT),
                                              args, 0, stream);
    if (e != hipSuccess) {
        enc_kernel<<<dim3(NBLK), dim3(NT), 0, stream>>>(
            dep, ne, gate_w, gate_b, map_w, map_b, w_ih, w_hh, b_ih, b_hh,
            flags, hv_ex, hin_ex, outp);
    }
    kF<<<dim3(512), dim3(256), 0, stream>>>(outp, lin11_w, lin11_b, lin12_w, lin12_b);
}

// Round 8
// 691.475 us; speedup vs baseline: 4.3102x; 1.5399x over previous
//
#include <hip/hip_runtime.h>

// DAG-GRU encoder, dispatch-independent persistent kernel + separate mu/logvar
// GEMV kernel. B=16, S=64, H=1024, C=16.
// enc_kernel: 8 groups (= blockIdx>>5) x 32 blocks; group g owns batches
// {2g,2g+1}. Each block: 32-o output tile, all 5 weight rows in VGPRs as fp16
// pairs (160 VGPRs; __launch_bounds__(512,2) grants the 256-VGPR budget that
// r7 lacked — r7 spilled all weights to scratch, WRITE_SIZE 68MB).
// Per step: phase A (G/M row GEMV + LDS masked scan -> h_in), phase B
// (gh GEMV + GRU pointwise -> hv). Cross-block exchange via sc0/sc1
// (Infinity-Cache) ops; single-writer flags, NO fences (r5/r6 bit-identical
// errors proved the exchange protocol itself was race-free).
// kF: separate kernel computing mu/logvar from the validated f32 hv in out.

#define NT 512
#define NBLK 256

typedef unsigned int uint;
typedef __attribute__((ext_vector_type(2))) _Float16 half2v;
typedef __attribute__((ext_vector_type(4))) uint uint4v;

__device__ __forceinline__ float fdot2(uint w, uint h, float acc) {
#if __has_builtin(__builtin_amdgcn_fdot2)
    return __builtin_amdgcn_fdot2(__builtin_bit_cast(half2v, w),
                                  __builtin_bit_cast(half2v, h), acc, false);
#else
    half2v a = __builtin_bit_cast(half2v, w);
    half2v b = __builtin_bit_cast(half2v, h);
    return acc + (float)a[0] * (float)b[0] + (float)a[1] * (float)b[1];
#endif
}

__device__ __forceinline__ uint packh2(float a, float b) {
    half2v h; h[0] = (_Float16)a; h[1] = (_Float16)b;
    return __builtin_bit_cast(uint, h);
}

__device__ __forceinline__ float sigm(float x) { return 1.0f / (1.0f + __expf(-x)); }
__device__ __forceinline__ float tanhfast(float x) { return 2.0f / (1.0f + __expf(-2.0f * x)) - 1.0f; }

// issue 8x dwordx4 device-coherent loads (bypass L1+L2 -> IF), NO wait
#define LD8_ISSUE(hx, baseptr)                                                 \
    asm volatile("global_load_dwordx4 %0, %8, off sc0 sc1\n\t"                 \
                 "global_load_dwordx4 %1, %8, off offset:16 sc0 sc1\n\t"       \
                 "global_load_dwordx4 %2, %8, off offset:32 sc0 sc1\n\t"       \
                 "global_load_dwordx4 %3, %8, off offset:48 sc0 sc1\n\t"       \
                 "global_load_dwordx4 %4, %8, off offset:64 sc0 sc1\n\t"       \
                 "global_load_dwordx4 %5, %8, off offset:80 sc0 sc1\n\t"       \
                 "global_load_dwordx4 %6, %8, off offset:96 sc0 sc1\n\t"       \
                 "global_load_dwordx4 %7, %8, off offset:112 sc0 sc1"          \
                 : "=&v"(hx[0]), "=&v"(hx[1]), "=&v"(hx[2]), "=&v"(hx[3]),     \
                   "=&v"(hx[4]), "=&v"(hx[5]), "=&v"(hx[6]), "=&v"(hx[7])      \
                 : "v"(baseptr) : "memory")

#define WAIT_VM8()                                          \
    asm volatile("s_waitcnt vmcnt(8)" ::: "memory");        \
    __builtin_amdgcn_sched_barrier(0)
#define WAIT_VM0()                                          \
    asm volatile("s_waitcnt vmcnt(0)" ::: "memory");        \
    __builtin_amdgcn_sched_barrier(0)

__device__ __forceinline__ void st_dev_wait(uint* p, uint v) {
    asm volatile("global_store_dword %0, %1, off sc0 sc1\n\ts_waitcnt vmcnt(0)"
                 :: "v"(p), "v"(v) : "memory");
}

__device__ __forceinline__ void st_flag(int* p, int v) {
    asm volatile("global_store_dword %0, %1, off sc0 sc1\n\ts_waitcnt vmcnt(0)"
                 :: "v"(p), "v"(v) : "memory");
}

// All threads call. Wave 0 (lanes 0..31) polls the group's 32 single-writer
// flag words until all >= gen; __syncthreads extends to the whole block.
__device__ __forceinline__ void wait_flags(const int* fl, int gen) {
    if (threadIdx.x < 64) {
        const int lane = threadIdx.x;
        bool done;
        do {
            int v = gen;
            if (lane < 32) {
                const int* pp = fl + lane;
                asm volatile("global_load_dword %0, %1, off sc0 sc1\n\ts_waitcnt vmcnt(0)"
                             : "=v"(v) : "v"(pp) : "memory");
            }
            done = __all(v >= gen);
        } while (!done);
    }
    __syncthreads();
}

__device__ __forceinline__ void loadw(uint* arr, const float* rowk) {
    const float4* s4 = (const float4*)rowk;
#pragma unroll
    for (int j = 0; j < 16; j++) {
        float4 v = s4[j];
        arr[2 * j]     = packh2(v.x, v.y);
        arr[2 * j + 1] = packh2(v.z, v.w);
    }
}

__global__ __launch_bounds__(NT, 2) void enc_kernel(
    const float* __restrict__ dep, const float* __restrict__ ne,
    const float* __restrict__ gate_w, const float* __restrict__ gate_b,
    const float* __restrict__ map_w, const float* __restrict__ map_b,
    const float* __restrict__ w_ih, const float* __restrict__ w_hh,
    const float* __restrict__ b_ih, const float* __restrict__ b_hh,
    int* __restrict__ flags, uint* __restrict__ hv_ex, uint* __restrict__ hin_ex,
    float* __restrict__ out)
{
    __shared__ __align__(16) float smem[13888];
    float* GM   = smem;                   // [4][64][33]: (mat*2+b, s, ol) f32
    float* red  = smem + 8448;            // 1536: cross-wave partials
    float* hbuf = smem + 9984;            // [2][32]: h_in / hv staging
    float* wihb = smem + 10048;           // [3][32][16] w_ih slice
    float* neb  = smem + 11584;           // [2][64][16] node_encoding slice
    uint*  depb = (uint*)(smem + 13632);  // [2][64][2] mask bits

    const int tid = threadIdx.x;
    const int bid = blockIdx.x;
    const int gid = bid >> 5;          // group = batch pair (dispatch-independent)
    const int p   = bid & 31;          // o-tile slot in group
    const int o0  = p * 32;
    const int bg0 = gid * 2;

    int*  fl   = flags  + gid * 32;
    uint* hvx  = hv_ex  + gid * 1024;  // [2][512] uints (fp16 pairs)
    uint* hinx = hin_ex + gid * 1024;

    const int w     = tid >> 6;        // wave = k-chunk of 128
    const int lane  = tid & 63;
    const int ol2   = lane >> 1;       // GEMV lane's o within tile
    const int kh    = lane & 1;
    const int og    = o0 + ol2;
    const int kbase = w * 128 + kh * 64;

    // ---- weights -> registers (fp16 packed), 160 VGPRs ----
    uint wG[32], wM[32], wR[32], wZ[32], wN[32];
    loadw(wG, gate_w + og * 1024 + kbase);
    loadw(wM, map_w + og * 1024 + kbase);
    loadw(wR, w_hh + og * 1024 + kbase);
    loadw(wZ, w_hh + (1024 + og) * 1024 + kbase);
    loadw(wN, w_hh + (2048 + og) * 1024 + kbase);

    // ---- LDS tables ----
    if (tid < 256) {  // dep bitmask: [b][t][half32]
        int b = tid >> 7, tt = (tid >> 1) & 63, hf = tid & 1;
        const float* dp = dep + (((bg0 + b) * 64 + tt) * 64) + hf * 32;
        uint bits = 0;
        for (int s = 0; s < 32; s++) bits |= (dp[s] != 0.0f) ? (1u << s) : 0u;
        depb[tid] = bits;
    }
#pragma unroll
    for (int e = 0; e < 3; e++) {     // w_ih slice [g][ol][c]
        int idx = tid + e * 512;
        int g = idx >> 9, r = idx & 511;
        wihb[idx] = w_ih[(g * 1024 + o0 + (r >> 4)) * 16 + (r & 15)];
    }
#pragma unroll
    for (int e = 0; e < 4; e++) {     // ne slice [b][t][c]
        int idx = tid + e * 512;
        int b = idx >> 10, r = idx & 1023;
        neb[idx] = ne[(bg0 + b) * 1024 + r];
    }

    // ---- hoisted per-thread scalars ----
    const int ol_s = (tid >> 3) & 31;
    const int b_s  = tid >> 8;
    const int soct = tid & 7;
    const float gb_s   = gate_b[o0 + ol_s];
    const float mb_s   = map_b[o0 + ol_s];
    const float base_s = sigm(gb_s) * mb_s;
    const int ol_c = tid & 31, b_c = (tid >> 5) & 1;
    const int oc = o0 + ol_c;
    const float bir = b_ih[oc], biz = b_ih[1024 + oc], bin_ = b_ih[2048 + oc];
    const float bhr = b_hh[oc], bhz = b_hh[1024 + oc], bhn = b_hh[2048 + oc];
    __syncthreads();

    for (int t = 0; t < 64; t++) {
        // ===== phase A: G/M row t-1 GEMV (regs) + masked scan -> h_in =====
        if (t > 0) {
            wait_flags(fl, 2 * t);     // hv of step t-1 published everywhere
            float aG0 = 0, aG1 = 0, aM0 = 0, aM1 = 0;
            {
                uint4v hxA[8], hxB[8];
                LD8_ISSUE(hxA, hvx + w * 64 + kh * 32);        // b0 hv slice
                LD8_ISSUE(hxB, hvx + 512 + w * 64 + kh * 32);  // b1 hv slice
                WAIT_VM8();
#pragma unroll
                for (int j = 0; j < 8; j++)
#pragma unroll
                    for (int q = 0; q < 4; q++) {
                        uint h = hxA[j][q];
                        aG0 = fdot2(wG[j * 4 + q], h, aG0);
                        aM0 = fdot2(wM[j * 4 + q], h, aM0);
                    }
                WAIT_VM0();
#pragma unroll
                for (int j = 0; j < 8; j++)
#pragma unroll
                    for (int q = 0; q < 4; q++) {
                        uint h = hxB[j][q];
                        aG1 = fdot2(wG[j * 4 + q], h, aG1);
                        aM1 = fdot2(wM[j * 4 + q], h, aM1);
                    }
            }
            aG0 += __shfl_xor(aG0, 1, 64); aG1 += __shfl_xor(aG1, 1, 64);
            aM0 += __shfl_xor(aM0, 1, 64); aM1 += __shfl_xor(aM1, 1, 64);
            if (kh == 0) {
                red[(w * 4 + 0) * 32 + ol2] = aG0;
                red[(w * 4 + 1) * 32 + ol2] = aG1;
                red[(w * 4 + 2) * 32 + ol2] = aM0;
                red[(w * 4 + 3) * 32 + ol2] = aM1;
            }
            __syncthreads();
            if (tid < 128) {   // mb2 = tid>>5: {G b0, G b1, M b0, M b1}
                int mb2 = tid >> 5, olr = tid & 31;
                float s = 0;
#pragma unroll
                for (int ww = 0; ww < 8; ww++) s += red[(ww * 4 + mb2) * 32 + olr];
                GM[(mb2 * 64 + (t - 1)) * 33 + olr] = s;
            }
            __syncthreads();
        }

        {   // masked scan: 8 threads per (b,o), 8 s each; GM in LDS
            uint bl = depb[b_s * 128 + t * 2 + (soct >> 2)];
            uint bits8 = (bl >> ((soct & 3) * 8)) & 0xFFu;
            const float* Gp = GM + (b_s * 64 + soct * 8) * 33 + ol_s;
            const float* Mp = GM + ((2 + b_s) * 64 + soct * 8) * 33 + ol_s;
            float part = 0.0f;
#pragma unroll
            for (int j = 0; j < 8; j++) {
                float Gv = Gp[j * 33], Mv = Mp[j * 33];
                float term = ((bits8 >> j) & 1u) ? (sigm(Gv + gb_s) * (Mv + mb_s)) : base_s;
                part += term;
            }
            part += __shfl_xor(part, 1, 64);
            part += __shfl_xor(part, 2, 64);
            part += __shfl_xor(part, 4, 64);
            if ((tid & 7) == 0) hbuf[b_s * 32 + ol_s] = part;
        }
        __syncthreads();
        if (tid < 32) {   // publish h_in slice (fp16 pairs)
            int bb = tid >> 4, j = tid & 15;
            uint pk = packh2(hbuf[bb * 32 + 2 * j], hbuf[bb * 32 + 2 * j + 1]);
            st_dev_wait(hinx + bb * 512 + p * 16 + j, pk);
        }
        __syncthreads();
        if (tid == 0) st_flag(fl + p, 2 * t + 1);

        // ===== phase B: gh GEMV (regs) + GRU pointwise -> hv =====
        wait_flags(fl, 2 * t + 1);
        float ar0 = 0, ar1 = 0, az0 = 0, az1 = 0, an0 = 0, an1 = 0;
        {
            uint4v hxA[8], hxB[8];
            LD8_ISSUE(hxA, hinx + w * 64 + kh * 32);
            LD8_ISSUE(hxB, hinx + 512 + w * 64 + kh * 32);
            WAIT_VM8();
#pragma unroll
            for (int j = 0; j < 8; j++)
#pragma unroll
                for (int q = 0; q < 4; q++) {
                    uint h = hxA[j][q];
                    ar0 = fdot2(wR[j * 4 + q], h, ar0);
                    az0 = fdot2(wZ[j * 4 + q], h, az0);
                    an0 = fdot2(wN[j * 4 + q], h, an0);
                }
            WAIT_VM0();
#pragma unroll
            for (int j = 0; j < 8; j++)
#pragma unroll
                for (int q = 0; q < 4; q++) {
                    uint h = hxB[j][q];
                    ar1 = fdot2(wR[j * 4 + q], h, ar1);
                    az1 = fdot2(wZ[j * 4 + q], h, az1);
                    an1 = fdot2(wN[j * 4 + q], h, an1);
                }
        }
        ar0 += __shfl_xor(ar0, 1, 64); ar1 += __shfl_xor(ar1, 1, 64);
        az0 += __shfl_xor(az0, 1, 64); az1 += __shfl_xor(az1, 1, 64);
        an0 += __shfl_xor(an0, 1, 64); an1 += __shfl_xor(an1, 1, 64);
        if (kh == 0) {
            red[(w * 6 + 0) * 32 + ol2] = ar0;
            red[(w * 6 + 1) * 32 + ol2] = ar1;
            red[(w * 6 + 2) * 32 + ol2] = az0;
            red[(w * 6 + 3) * 32 + ol2] = az1;
            red[(w * 6 + 4) * 32 + ol2] = an0;
            red[(w * 6 + 5) * 32 + ol2] = an1;
        }
        __syncthreads();
        if (tid < 64) {
            float ghr = 0, ghz = 0, ghn = 0;
#pragma unroll
            for (int ww = 0; ww < 8; ww++) {
                ghr += red[(ww * 6 + 0 + b_c) * 32 + ol_c];
                ghz += red[(ww * 6 + 2 + b_c) * 32 + ol_c];
                ghn += red[(ww * 6 + 4 + b_c) * 32 + ol_c];
            }
            float gi0 = 0, gi1 = 0, gi2 = 0;
#pragma unroll
            for (int c = 0; c < 16; c++) {
                float xv = neb[b_c * 1024 + t * 16 + c];
                gi0 += wihb[ol_c * 16 + c] * xv;
                gi1 += wihb[512 + ol_c * 16 + c] * xv;
                gi2 += wihb[1024 + ol_c * 16 + c] * xv;
            }
            float h_in = hbuf[b_c * 32 + ol_c];
            float r = sigm(gi0 + bir + ghr + bhr);
            float z = sigm(gi1 + biz + ghz + bhz);
            float n = tanhfast(gi2 + bin_ + r * (ghn + bhn));
            float hv = (1.0f - z) * n + z * h_in;
            if (t == 63) out[(bg0 + b_c) * 1024 + oc] = hv;
            hbuf[b_c * 32 + ol_c] = hv;
        }
        __syncthreads();
        if (t < 63) {
            if (tid < 32) {   // publish hv slice
                int bb = tid >> 4, j = tid & 15;
                uint pk = packh2(hbuf[bb * 32 + 2 * j], hbuf[bb * 32 + 2 * j + 1]);
                st_dev_wait(hvx + bb * 512 + p * 16 + j, pk);
            }
            __syncthreads();
            if (tid == 0) st_flag(fl + p, 2 * t + 2);
        }
    }
    // mu/logvar computed by kF (separate dispatch) from the f32 hv in out.
}

__device__ __forceinline__ float wave_sum(float v) {
    v += __shfl_xor(v, 32, 64);
    v += __shfl_xor(v, 16, 64);
    v += __shfl_xor(v, 8, 64);
    v += __shfl_xor(v, 4, 64);
    v += __shfl_xor(v, 2, 64);
    v += __shfl_xor(v, 1, 64);
    return v;
}

// mu/logvar: out[16K..32K) = hv @ l1w^T + b1, out[32K..48K) = hv @ l2w^T + b2.
__global__ __launch_bounds__(256) void kF(
    float* out, const float* __restrict__ w1, const float* __restrict__ b1,
    const float* __restrict__ w2, const float* __restrict__ b2)
{
    const int wid = threadIdx.x >> 6;
    const int kl = threadIdx.x & 63;
    const int o = blockIdx.x * 2 + (wid >> 1);
    const int b0 = (wid & 1) * 8;

    float w1v[16], w2v[16];
#pragma unroll
    for (int i = 0; i < 16; i++) {
        w1v[i] = w1[o * 1024 + kl + 64 * i];
        w2v[i] = w2[o * 1024 + kl + 64 * i];
    }
    for (int b = b0; b < b0 + 8; b++) {
        float p1 = 0.0f, p2 = 0.0f;
#pragma unroll
        for (int i = 0; i < 16; i++) {
            float h = out[b * 1024 + kl + 64 * i];
            p1 += h * w1v[i];
            p2 += h * w2v[i];
        }
        p1 = wave_sum(p1);
        p2 = wave_sum(p2);
        if (kl == 0) {
            out[16384 + b * 1024 + o] = p1 + b1[o];
            out[32768 + b * 1024 + o] = p2 + b2[o];
        }
    }
}

extern "C" void kernel_launch(void* const* d_in, const int* in_sizes, int n_in,
                              void* d_out, int out_size, void* d_ws, size_t ws_size,
                              hipStream_t stream) {
    const float* dep     = (const float*)d_in[0];
    const float* ne      = (const float*)d_in[1];
    const float* gate_w  = (const float*)d_in[2];
    const float* gate_b  = (const float*)d_in[3];
    const float* map_w   = (const float*)d_in[4];
    const float* map_b   = (const float*)d_in[5];
    const float* w_ih    = (const float*)d_in[6];
    const float* w_hh    = (const float*)d_in[7];
    const float* b_ih    = (const float*)d_in[8];
    const float* b_hh    = (const float*)d_in[9];
    const float* lin11_w = (const float*)d_in[10];
    const float* lin11_b = (const float*)d_in[11];
    const float* lin12_w = (const float*)d_in[12];
    const float* lin12_b = (const float*)d_in[13];

    int* wsI = (int*)d_ws;
    int* flags   = wsI;                      // [8][32] ints
    uint* hv_ex  = (uint*)(wsI + 256);       // [8][2][512]
    uint* hin_ex = hv_ex + 8192;             // [8][2][512]
    float* outp  = (float*)d_out;

    hipMemsetAsync((void*)flags, 0, 256 * 4, stream);

    void* args[] = {
        (void*)&dep, (void*)&ne, (void*)&gate_w, (void*)&gate_b,
        (void*)&map_w, (void*)&map_b, (void*)&w_ih, (void*)&w_hh,
        (void*)&b_ih, (void*)&b_hh,
        (void*)&flags, (void*)&hv_ex, (void*)&hin_ex, (void*)&outp,
    };
    hipError_t e = hipLaunchCooperativeKernel((void*)enc_kernel, dim3(NBLK), dim3(NT),
                                              args, 0, stream);
    if (e != hipSuccess) {
        enc_kernel<<<dim3(NBLK), dim3(NT), 0, stream>>>(
            dep, ne, gate_w, gate_b, map_w, map_b, w_ih, w_hh, b_ih, b_hh,
            flags, hv_ex, hin_ex, outp);
    }
    kF<<<dim3(512), dim3(256), 0, stream>>>(outp, lin11_w, lin11_b, lin12_w, lin12_b);
}